// Round 11
// baseline (85.625 us; speedup 1.0000x reference)
//
#include <hip/hip_runtime.h>

// 10 steps of anisotropic 2D heat stencil, 48x48, B=16384.
// Wave = image. Lane layout 16x4: (r,c)=(lane&15, lane>>4), patch 3x12 as
// 6 v2f/row -> packed v_pk_add/fma_f32 stencil math.
// Vertical halo: DPP row shifts with frozen reflect ghost as 'old' operand.
// Horizontal halo: 6 bpermutes/step, SOFTWARE-PIPELINED ONE STEP AHEAD
// (issued right after the producing row's update; consumed next step ->
// ~full step of latency cover instead of ~60 cycles).
// Horizontal shifted sums computed as 2 scalar v_add per pair (fresh dest
// pair, no alignment movs) instead of building shifted M[] pairs.
// Ghosts = reflect pad of the INITIAL state, frozen across steps.

typedef float v2f __attribute__((ext_vector_type(2)));

constexpr int NXY   = 48;
constexpr int CELLS = NXY * NXY;     // 2304
constexpr int NT    = 10;
constexpr int WPB   = 4;             // waves (images) per block
constexpr int TPB   = 64 * WPB;

// lane i <- lane i-1 within each 16-lane DPP row; invalid (i%16==0) keeps oldv
__device__ __forceinline__ float dpp_up(float oldv, float src) {
    return __int_as_float(__builtin_amdgcn_update_dpp(
        __float_as_int(oldv), __float_as_int(src), 0x111, 0xF, 0xF, false));
}
// lane i <- lane i+1; invalid (i%16==15) keeps oldv
__device__ __forceinline__ float dpp_dn(float oldv, float src) {
    return __int_as_float(__builtin_amdgcn_update_dpp(
        __float_as_int(oldv), __float_as_int(src), 0x101, 0xF, 0xF, false));
}
__device__ __forceinline__ v2f dpp_up2(v2f o, v2f s) {
    v2f r; r.x = dpp_up(o.x, s.x); r.y = dpp_up(o.y, s.y); return r;
}
__device__ __forceinline__ v2f dpp_dn2(v2f o, v2f s) {
    v2f r; r.x = dpp_dn(o.x, s.x); r.y = dpp_dn(o.y, s.y); return r;
}

__global__ __launch_bounds__(TPB)
__attribute__((amdgpu_waves_per_eu(4, 8)))
void pde_heat_kernel(
    const float* __restrict__ u0,
    const float* __restrict__ aw,
    const float* __restrict__ bw,
    float* __restrict__ out)
{
    const int lane = threadIdx.x & 63;
    const int img  = blockIdx.x * WPB + (threadIdx.x >> 6);
    const int r = lane & 15;         // patch-row strip (16 strips of 3 rows)
    const int c = lane >> 4;         // patch-col strip (4 strips of 12 cols)
    const float4* __restrict__ u4 = (const float4*)(u0 + (long long)img * CELLS);
    float4*       __restrict__ o4 = (float4*)(out + (long long)img * CELLS);

    const int fb = r * 36 + c * 3;   // float4 index of patch (row0, col0)

    // ---- direct load: 9 x global_load_dwordx4 -> 6 x v2f per row ----
    v2f v[3][6];
    #pragma unroll
    for (int ii = 0; ii < 3; ++ii)
        #pragma unroll
        for (int k = 0; k < 3; ++k) {
            float4 t = u4[fb + 12 * ii + k];
            v[ii][2*k]   = (v2f){t.x, t.y};
            v[ii][2*k+1] = (v2f){t.z, t.w};
        }

    // ---- coefficients (v_sin/v_cos take REVOLUTIONS: sin(2pi*x) = v_sin(x)) ----
    // alpha(i) scales axis-0 diff: 0.5*dt/dx^2 = 1.152 ; beta(j): dt/dy^2 = 2.304
    const float a0 = aw[0], a1 = aw[1], a2 = aw[2];
    const float b0 = bw[0], b1 = bw[1], b2 = bw[2];
    float ca[3];
    #pragma unroll
    for (int ii = 0; ii < 3; ++ii) {
        float y = (float)(3 * r + ii) * (1.0f / 47.0f);
        ca[ii] = 1.152f * (a0 + a1 * __builtin_amdgcn_sinf(y)
                              + a2 * __builtin_amdgcn_sinf(2.0f * y));
    }
    v2f cb2[6];
    #pragma unroll
    for (int k = 0; k < 6; ++k) {
        float x0 = (float)(12 * c + 2 * k)     * (1.0f / 47.0f);
        float x1 = (float)(12 * c + 2 * k + 1) * (1.0f / 47.0f);
        cb2[k].x = 2.304f * (b0 + b1 * __builtin_amdgcn_cosf(x0)
                                + b2 * __builtin_amdgcn_cosf(2.0f * x0));
        cb2[k].y = 2.304f * (b0 + b1 * __builtin_amdgcn_cosf(x1)
                                + b2 * __builtin_amdgcn_cosf(2.0f * x1));
    }

    // ---- frozen reflect ghosts (from INITIAL state) ----
    // top (r==0): u0 row 1 = own v[1]; bottom (r==15): row 46 = 3*15+1 = own v[1]
    // left (c==0): col 1 = v[ii][0].y; right (c==3): col 46 = elem 10 = v[ii][5].x
    v2f gV[6];
    #pragma unroll
    for (int k = 0; k < 6; ++k) gV[k] = v[1][k];
    float gH[3];
    #pragma unroll
    for (int ii = 0; ii < 3; ++ii) gH[ii] = (c == 0) ? v[ii][0].y : v[ii][5].x;

    const int laneL = lane - 16, laneR = lane + 16;
    const bool cLft = (c == 0), cRgt = (c == 3);

    // ---- prime the shuffle pipeline for step 0 ----
    float hlp[3], hrp[3];                 // raw shuffled halos for the NEXT step
    #pragma unroll
    for (int ii = 0; ii < 3; ++ii) {
        hlp[ii] = __shfl(v[ii][5].y, laneL);   // left neighbor's col 11
        hrp[ii] = __shfl(v[ii][0].x, laneR);   // right neighbor's col 0
    }

    // ---- time loop: FULLY UNROLLED; shuffles pipelined one step ahead ----
    #pragma unroll
    for (int t = 0; t < NT; ++t) {
        // select ghosts for this step's horizontal halos (shuffles done last step)
        float hl[3], hr[3];
        #pragma unroll
        for (int ii = 0; ii < 3; ++ii) {
            hl[ii] = cLft ? gH[ii] : hlp[ii];
            hr[ii] = cRgt ? gH[ii] : hrp[ii];
        }

        // vertical halos (old values; dpp old-operand = frozen ghost)
        v2f hb[6], ab[6];
        #pragma unroll
        for (int k = 0; k < 6; ++k) hb[k] = dpp_dn2(gV[k], v[0][k]);
        #pragma unroll
        for (int k = 0; k < 6; ++k) ab[k] = dpp_up2(gV[k], v[2][k]);

        #pragma unroll
        for (int ii = 0; ii < 3; ++ii) {
            const float hlv = hl[ii], hrv = hr[ii];

            v2f nrow[6];
            #pragma unroll
            for (int k = 0; k < 6; ++k) {
                v2f cv    = v[ii][k];
                v2f below = (ii < 2) ? v[ii + 1][k] : hb[k];
                v2f s1 = ab[k] + below;                       // pk_add
                // horizontal shifted sum: two scalar adds into a fresh pair
                v2f s2;
                s2.x = ((k > 0) ? v[ii][k - 1].y : hlv) + v[ii][k].y;
                s2.y = v[ii][k].x + ((k < 5) ? v[ii][k + 1].x : hrv);
                v2f uxx = s1 - 2.0f * cv;                     // pk_fma
                v2f uyy = s2 - 2.0f * cv;                     // pk_fma
                nrow[k] = cv + ca[ii] * uxx + cb2[k] * uyy;   // 2x pk_fma
            }
            // rotate: renames under full unroll
            #pragma unroll
            for (int k = 0; k < 6; ++k) { ab[k] = v[ii][k]; v[ii][k] = nrow[k]; }

            // issue NEXT step's shuffles for this row now that v[ii] is final:
            // a full step (~300+ cycles) covers the ~100-cycle bpermute latency
            if (t < NT - 1) {
                hlp[ii] = __shfl(v[ii][5].y, laneL);
                hrp[ii] = __shfl(v[ii][0].x, laneR);
            }
        }
    }

    // ---- direct store: 9 x global_store_dwordx4 ----
    #pragma unroll
    for (int ii = 0; ii < 3; ++ii)
        #pragma unroll
        for (int k = 0; k < 3; ++k) {
            float4 t;
            t.x = v[ii][2*k].x;   t.y = v[ii][2*k].y;
            t.z = v[ii][2*k+1].x; t.w = v[ii][2*k+1].y;
            o4[fb + 12 * ii + k] = t;
        }
}

extern "C" void kernel_launch(void* const* d_in, const int* in_sizes, int n_in,
                              void* d_out, int out_size, void* d_ws, size_t ws_size,
                              hipStream_t stream) {
    const float* u0 = (const float*)d_in[0];
    const float* aw = (const float*)d_in[1];
    const float* bw = (const float*)d_in[2];
    float* out = (float*)d_out;

    const int B = in_sizes[0] / CELLS;   // 16384
    pde_heat_kernel<<<B / WPB, TPB, 0, stream>>>(u0, aw, bw, out);
}

// Round 12
// 83.785 us; speedup vs baseline: 1.0220x; 1.0220x over previous
//
#include <hip/hip_runtime.h>

// 10 steps of anisotropic 2D heat stencil, 48x48, B=16384.
// Wave = image. Lane layout 16x4: (r,c)=(lane&15, lane>>4), patch 3x12 as
// 6 v2f/row -> packed v_pk_add/fma_f32 stencil math.
// ROUND 12: double-buffered Jacobi (v->w, w->v) with a ROLLED x2 loop body:
//  - zero rotation/save copies (src never aliases dst)
//  - ~400-instr loop body stays I$-resident (round 10's full unroll was ~30KB)
//  - shuffles for step t+1 issued right after dst finalizes (full-step cover)
//  - waves_per_eu(2,4): 256-reg allocator budget -> no squeeze copies, no spill
// Vertical halo: DPP row shifts, frozen reflect ghost as 'old' operand.
// Ghosts = reflect pad of the INITIAL state (reference pads once before scan).

typedef float v2f __attribute__((ext_vector_type(2)));

constexpr int NXY   = 48;
constexpr int CELLS = NXY * NXY;     // 2304
constexpr int NT    = 10;
constexpr int WPB   = 4;             // waves (images) per block
constexpr int TPB   = 64 * WPB;

// lane i <- lane i-1 within each 16-lane DPP row; invalid (i%16==0) keeps oldv
__device__ __forceinline__ float dpp_up(float oldv, float src) {
    return __int_as_float(__builtin_amdgcn_update_dpp(
        __float_as_int(oldv), __float_as_int(src), 0x111, 0xF, 0xF, false));
}
// lane i <- lane i+1; invalid (i%16==15) keeps oldv
__device__ __forceinline__ float dpp_dn(float oldv, float src) {
    return __int_as_float(__builtin_amdgcn_update_dpp(
        __float_as_int(oldv), __float_as_int(src), 0x101, 0xF, 0xF, false));
}
__device__ __forceinline__ v2f dpp_up2(v2f o, v2f s) {
    v2f r; r.x = dpp_up(o.x, s.x); r.y = dpp_up(o.y, s.y); return r;
}
__device__ __forceinline__ v2f dpp_dn2(v2f o, v2f s) {
    v2f r; r.x = dpp_dn(o.x, s.x); r.y = dpp_dn(o.y, s.y); return r;
}

__global__ __launch_bounds__(TPB)
__attribute__((amdgpu_waves_per_eu(2, 4)))
void pde_heat_kernel(
    const float* __restrict__ u0,
    const float* __restrict__ aw,
    const float* __restrict__ bw,
    float* __restrict__ out)
{
    const int lane = threadIdx.x & 63;
    const int img  = blockIdx.x * WPB + (threadIdx.x >> 6);
    const int r = lane & 15;         // patch-row strip (16 strips of 3 rows)
    const int c = lane >> 4;         // patch-col strip (4 strips of 12 cols)
    const float4* __restrict__ u4 = (const float4*)(u0 + (long long)img * CELLS);
    float4*       __restrict__ o4 = (float4*)(out + (long long)img * CELLS);

    const int fb = r * 36 + c * 3;   // float4 index of patch (row0, col0)

    // ---- direct load: 9 x global_load_dwordx4 -> 6 x v2f per row ----
    v2f v[3][6], w[3][6];
    #pragma unroll
    for (int ii = 0; ii < 3; ++ii)
        #pragma unroll
        for (int k = 0; k < 3; ++k) {
            float4 t = u4[fb + 12 * ii + k];
            v[ii][2*k]   = (v2f){t.x, t.y};
            v[ii][2*k+1] = (v2f){t.z, t.w};
        }

    // ---- coefficients (v_sin/v_cos take REVOLUTIONS: sin(2pi*x) = v_sin(x)) ----
    // alpha(i) scales axis-0 diff: 0.5*dt/dx^2 = 1.152 ; beta(j): dt/dy^2 = 2.304
    const float a0 = aw[0], a1 = aw[1], a2 = aw[2];
    const float b0 = bw[0], b1 = bw[1], b2 = bw[2];
    float ca[3];
    #pragma unroll
    for (int ii = 0; ii < 3; ++ii) {
        float y = (float)(3 * r + ii) * (1.0f / 47.0f);
        ca[ii] = 1.152f * (a0 + a1 * __builtin_amdgcn_sinf(y)
                              + a2 * __builtin_amdgcn_sinf(2.0f * y));
    }
    v2f cb2[6];
    #pragma unroll
    for (int k = 0; k < 6; ++k) {
        float x0 = (float)(12 * c + 2 * k)     * (1.0f / 47.0f);
        float x1 = (float)(12 * c + 2 * k + 1) * (1.0f / 47.0f);
        cb2[k].x = 2.304f * (b0 + b1 * __builtin_amdgcn_cosf(x0)
                                + b2 * __builtin_amdgcn_cosf(2.0f * x0));
        cb2[k].y = 2.304f * (b0 + b1 * __builtin_amdgcn_cosf(x1)
                                + b2 * __builtin_amdgcn_cosf(2.0f * x1));
    }

    // ---- frozen reflect ghosts (from INITIAL state) ----
    // top (r==0): u0 row 1 = own v[1]; bottom (r==15): row 46 = 3*15+1 = own v[1]
    // left (c==0): col 1 = v[ii][0].y; right (c==3): col 46 = elem 10 = v[ii][5].x
    v2f gV[6];
    #pragma unroll
    for (int k = 0; k < 6; ++k) gV[k] = v[1][k];
    float gH[3];
    #pragma unroll
    for (int ii = 0; ii < 3; ++ii) gH[ii] = (c == 0) ? v[ii][0].y : v[ii][5].x;

    const int laneL = lane - 16, laneR = lane + 16;
    const bool cLft = (c == 0), cRgt = (c == 3);

    // raw shuffled horizontal halos for the NEXT step (pipelined)
    float hlp[3], hrp[3];
    #pragma unroll
    for (int ii = 0; ii < 3; ++ii) {
        hlp[ii] = __shfl(v[ii][5].y, laneL);   // left neighbor's col 11
        hrp[ii] = __shfl(v[ii][0].x, laneR);   // right neighbor's col 0
    }

    // one Jacobi step: src (all old) -> dst, then issue dst's shuffles
    auto step = [&](const v2f (&src)[3][6], v2f (&dst)[3][6]) {
        float hl[3], hr[3];
        #pragma unroll
        for (int ii = 0; ii < 3; ++ii) {
            hl[ii] = cLft ? gH[ii] : hlp[ii];
            hr[ii] = cRgt ? gH[ii] : hrp[ii];
        }
        // row 0 (needs row above patch; narrow ab liveness)
        {
            v2f ab[6];
            #pragma unroll
            for (int k = 0; k < 6; ++k) ab[k] = dpp_up2(gV[k], src[2][k]);
            #pragma unroll
            for (int k = 0; k < 6; ++k) {
                v2f cv = src[0][k];
                v2f s1 = ab[k] + src[1][k];
                v2f s2;
                s2.x = ((k > 0) ? src[0][k-1].y : hl[0]) + cv.y;
                s2.y = cv.x + ((k < 5) ? src[0][k+1].x : hr[0]);
                v2f uxx = s1 - 2.0f * cv;
                v2f uyy = s2 - 2.0f * cv;
                dst[0][k] = cv + ca[0] * uxx + cb2[k] * uyy;
            }
        }
        // row 1 (fully local)
        #pragma unroll
        for (int k = 0; k < 6; ++k) {
            v2f cv = src[1][k];
            v2f s1 = src[0][k] + src[2][k];
            v2f s2;
            s2.x = ((k > 0) ? src[1][k-1].y : hl[1]) + cv.y;
            s2.y = cv.x + ((k < 5) ? src[1][k+1].x : hr[1]);
            v2f uxx = s1 - 2.0f * cv;
            v2f uyy = s2 - 2.0f * cv;
            dst[1][k] = cv + ca[1] * uxx + cb2[k] * uyy;
        }
        // row 2 (needs row below patch; narrow hb liveness)
        {
            v2f hb[6];
            #pragma unroll
            for (int k = 0; k < 6; ++k) hb[k] = dpp_dn2(gV[k], src[0][k]);
            #pragma unroll
            for (int k = 0; k < 6; ++k) {
                v2f cv = src[2][k];
                v2f s1 = src[1][k] + hb[k];
                v2f s2;
                s2.x = ((k > 0) ? src[2][k-1].y : hl[2]) + cv.y;
                s2.y = cv.x + ((k < 5) ? src[2][k+1].x : hr[2]);
                v2f uxx = s1 - 2.0f * cv;
                v2f uyy = s2 - 2.0f * cv;
                dst[2][k] = cv + ca[2] * uxx + cb2[k] * uyy;
            }
        }
        // issue NEXT step's shuffles now that dst is final (full-step cover)
        #pragma unroll
        for (int ii = 0; ii < 3; ++ii) {
            hlp[ii] = __shfl(dst[ii][5].y, laneL);
            hrp[ii] = __shfl(dst[ii][0].x, laneR);
        }
    };

    // ---- time loop: rolled x2 (NT=10 even -> final state lands in v) ----
    #pragma unroll 1
    for (int it = 0; it < NT / 2; ++it) {
        step(v, w);
        step(w, v);
    }

    // ---- direct store: 9 x global_store_dwordx4 ----
    #pragma unroll
    for (int ii = 0; ii < 3; ++ii)
        #pragma unroll
        for (int k = 0; k < 3; ++k) {
            float4 t;
            t.x = v[ii][2*k].x;   t.y = v[ii][2*k].y;
            t.z = v[ii][2*k+1].x; t.w = v[ii][2*k+1].y;
            o4[fb + 12 * ii + k] = t;
        }
}

extern "C" void kernel_launch(void* const* d_in, const int* in_sizes, int n_in,
                              void* d_out, int out_size, void* d_ws, size_t ws_size,
                              hipStream_t stream) {
    const float* u0 = (const float*)d_in[0];
    const float* aw = (const float*)d_in[1];
    const float* bw = (const float*)d_in[2];
    float* out = (float*)d_out;

    const int B = in_sizes[0] / CELLS;   // 16384
    pde_heat_kernel<<<B / WPB, TPB, 0, stream>>>(u0, aw, bw, out);
}

// Round 13
// 79.450 us; speedup vs baseline: 1.0777x; 1.0546x over previous
//
#include <hip/hip_runtime.h>

// 10 steps of anisotropic 2D heat stencil, 48x48, B=16384.
// Wave = image. Lane layout 16x4: (r,c)=(lane&15, lane>>4), patch 3x12 as
// 6 v2f/row -> packed v_pk_add/fma_f32 stencil math.
// Double-buffered Jacobi (v->w, w->v), rolled x2 body (I$-resident ~3KB).
// ROUND 13: SELF-TIED DPP GHOSTS. For row_shr:1 the DPP-invalid lanes are
// exactly r==0; for row_shl:1 exactly r==15 - the boundary lanes. ab/hb are
// persistent registers initialized to the frozen reflect ghost (initial row
// 1 / 46 = own v[1]); each step ab[k]=update_dpp(ab[k], src[2][k]) compiles
// to ONE tied-dest v_mov_b32_dpp: valid lanes <- neighbor row, boundary
// lanes retain frozen ghost. Boundary condition costs zero instructions.
// Horizontal halo: 6 bpermutes/step pipelined one step ahead + cndmask.
// Ghosts = reflect pad of the INITIAL state (reference pads once).

typedef float v2f __attribute__((ext_vector_type(2)));

constexpr int NXY   = 48;
constexpr int CELLS = NXY * NXY;     // 2304
constexpr int NT    = 10;
constexpr int WPB   = 4;             // waves (images) per block
constexpr int TPB   = 64 * WPB;

// lane i <- lane i-1 within each 16-lane DPP row; invalid (i%16==0) keeps oldv
__device__ __forceinline__ float dpp_up(float oldv, float src) {
    return __int_as_float(__builtin_amdgcn_update_dpp(
        __float_as_int(oldv), __float_as_int(src), 0x111, 0xF, 0xF, false));
}
// lane i <- lane i+1; invalid (i%16==15) keeps oldv
__device__ __forceinline__ float dpp_dn(float oldv, float src) {
    return __int_as_float(__builtin_amdgcn_update_dpp(
        __float_as_int(oldv), __float_as_int(src), 0x101, 0xF, 0xF, false));
}

__global__ __launch_bounds__(TPB)
__attribute__((amdgpu_waves_per_eu(2, 4)))
void pde_heat_kernel(
    const float* __restrict__ u0,
    const float* __restrict__ aw,
    const float* __restrict__ bw,
    float* __restrict__ out)
{
    const int lane = threadIdx.x & 63;
    const int img  = blockIdx.x * WPB + (threadIdx.x >> 6);
    const int r = lane & 15;         // patch-row strip (16 strips of 3 rows)
    const int c = lane >> 4;         // patch-col strip (4 strips of 12 cols)
    const float4* __restrict__ u4 = (const float4*)(u0 + (long long)img * CELLS);
    float4*       __restrict__ o4 = (float4*)(out + (long long)img * CELLS);

    const int fb = r * 36 + c * 3;   // float4 index of patch (row0, col0)

    // ---- direct load: 9 x global_load_dwordx4 -> 6 x v2f per row ----
    v2f v[3][6], w[3][6];
    #pragma unroll
    for (int ii = 0; ii < 3; ++ii)
        #pragma unroll
        for (int k = 0; k < 3; ++k) {
            float4 t = u4[fb + 12 * ii + k];
            v[ii][2*k]   = (v2f){t.x, t.y};
            v[ii][2*k+1] = (v2f){t.z, t.w};
        }

    // ---- coefficients (v_sin/v_cos take REVOLUTIONS: sin(2pi*x) = v_sin(x)) ----
    // alpha(i) scales axis-0 diff: 0.5*dt/dx^2 = 1.152 ; beta(j): dt/dy^2 = 2.304
    const float a0 = aw[0], a1 = aw[1], a2 = aw[2];
    const float b0 = bw[0], b1 = bw[1], b2 = bw[2];
    float ca[3];
    #pragma unroll
    for (int ii = 0; ii < 3; ++ii) {
        float y = (float)(3 * r + ii) * (1.0f / 47.0f);
        ca[ii] = 1.152f * (a0 + a1 * __builtin_amdgcn_sinf(y)
                              + a2 * __builtin_amdgcn_sinf(2.0f * y));
    }
    v2f cb2[6];
    #pragma unroll
    for (int k = 0; k < 6; ++k) {
        float x0 = (float)(12 * c + 2 * k)     * (1.0f / 47.0f);
        float x1 = (float)(12 * c + 2 * k + 1) * (1.0f / 47.0f);
        cb2[k].x = 2.304f * (b0 + b1 * __builtin_amdgcn_cosf(x0)
                                + b2 * __builtin_amdgcn_cosf(2.0f * x0));
        cb2[k].y = 2.304f * (b0 + b1 * __builtin_amdgcn_cosf(x1)
                                + b2 * __builtin_amdgcn_cosf(2.0f * x1));
    }

    // ---- persistent halo registers, initialized to the frozen ghost ----
    // top ghost (r==0) = u0 row 1 = own v[1]; bottom ghost (r==15) = u0 row
    // 46 = 3*15+1 = own v[1]. Boundary lanes' ab/hb are NEVER overwritten by
    // the self-tied dpp (they are the invalid lanes) -> stay frozen.
    v2f ab[6], hb[6];
    #pragma unroll
    for (int k = 0; k < 6; ++k) { ab[k] = v[1][k]; hb[k] = v[1][k]; }

    float gH[3];   // frozen horizontal ghosts: col 1 / col 46 (own initial)
    #pragma unroll
    for (int ii = 0; ii < 3; ++ii) gH[ii] = (c == 0) ? v[ii][0].y : v[ii][5].x;

    const int laneL = lane - 16, laneR = lane + 16;
    const bool cLft = (c == 0), cRgt = (c == 3);

    // raw shuffled horizontal halos for the NEXT step (pipelined)
    float hlp[3], hrp[3];
    #pragma unroll
    for (int ii = 0; ii < 3; ++ii) {
        hlp[ii] = __shfl(v[ii][5].y, laneL);   // left neighbor's col 11
        hrp[ii] = __shfl(v[ii][0].x, laneR);   // right neighbor's col 0
    }

    // one Jacobi step: src (all old) -> dst, then issue dst's shuffles
    auto step = [&](const v2f (&src)[3][6], v2f (&dst)[3][6]) {
        // vertical halos: ONE tied-dest v_mov_b32_dpp each; boundary lanes
        // (dpp-invalid) retain previous contents = frozen ghost
        #pragma unroll
        for (int k = 0; k < 6; ++k) {
            ab[k].x = dpp_up(ab[k].x, src[2][k].x);
            ab[k].y = dpp_up(ab[k].y, src[2][k].y);
            hb[k].x = dpp_dn(hb[k].x, src[0][k].x);
            hb[k].y = dpp_dn(hb[k].y, src[0][k].y);
        }
        float hl[3], hr[3];
        #pragma unroll
        for (int ii = 0; ii < 3; ++ii) {
            hl[ii] = cLft ? gH[ii] : hlp[ii];
            hr[ii] = cRgt ? gH[ii] : hrp[ii];
        }
        // row 0 (row above = ab)
        #pragma unroll
        for (int k = 0; k < 6; ++k) {
            v2f cv = src[0][k];
            v2f s1 = ab[k] + src[1][k];
            v2f s2;
            s2.x = ((k > 0) ? src[0][k-1].y : hl[0]) + cv.y;
            s2.y = cv.x + ((k < 5) ? src[0][k+1].x : hr[0]);
            v2f uxx = s1 - 2.0f * cv;
            v2f uyy = s2 - 2.0f * cv;
            dst[0][k] = cv + ca[0] * uxx + cb2[k] * uyy;
        }
        // row 1 (fully local)
        #pragma unroll
        for (int k = 0; k < 6; ++k) {
            v2f cv = src[1][k];
            v2f s1 = src[0][k] + src[2][k];
            v2f s2;
            s2.x = ((k > 0) ? src[1][k-1].y : hl[1]) + cv.y;
            s2.y = cv.x + ((k < 5) ? src[1][k+1].x : hr[1]);
            v2f uxx = s1 - 2.0f * cv;
            v2f uyy = s2 - 2.0f * cv;
            dst[1][k] = cv + ca[1] * uxx + cb2[k] * uyy;
        }
        // row 2 (row below = hb)
        #pragma unroll
        for (int k = 0; k < 6; ++k) {
            v2f cv = src[2][k];
            v2f s1 = src[1][k] + hb[k];
            v2f s2;
            s2.x = ((k > 0) ? src[2][k-1].y : hl[2]) + cv.y;
            s2.y = cv.x + ((k < 5) ? src[2][k+1].x : hr[2]);
            v2f uxx = s1 - 2.0f * cv;
            v2f uyy = s2 - 2.0f * cv;
            dst[2][k] = cv + ca[2] * uxx + cb2[k] * uyy;
        }
        // issue NEXT step's shuffles now that dst is final (full-step cover)
        #pragma unroll
        for (int ii = 0; ii < 3; ++ii) {
            hlp[ii] = __shfl(dst[ii][5].y, laneL);
            hrp[ii] = __shfl(dst[ii][0].x, laneR);
        }
    };

    // ---- time loop: rolled x2 (NT=10 even -> final state lands in v) ----
    #pragma unroll 1
    for (int it = 0; it < NT / 2; ++it) {
        step(v, w);
        step(w, v);
    }

    // ---- direct store: 9 x global_store_dwordx4 ----
    #pragma unroll
    for (int ii = 0; ii < 3; ++ii)
        #pragma unroll
        for (int k = 0; k < 3; ++k) {
            float4 t;
            t.x = v[ii][2*k].x;   t.y = v[ii][2*k].y;
            t.z = v[ii][2*k+1].x; t.w = v[ii][2*k+1].y;
            o4[fb + 12 * ii + k] = t;
        }
}

extern "C" void kernel_launch(void* const* d_in, const int* in_sizes, int n_in,
                              void* d_out, int out_size, void* d_ws, size_t ws_size,
                              hipStream_t stream) {
    const float* u0 = (const float*)d_in[0];
    const float* aw = (const float*)d_in[1];
    const float* bw = (const float*)d_in[2];
    float* out = (float*)d_out;

    const int B = in_sizes[0] / CELLS;   // 16384
    pde_heat_kernel<<<B / WPB, TPB, 0, stream>>>(u0, aw, bw, out);
}

// Round 14
// 78.925 us; speedup vs baseline: 1.0849x; 1.0067x over previous
//
#include <hip/hip_runtime.h>

// 10 steps of anisotropic 2D heat stencil, 48x48, B=16384.
// Wave = image. Lane layout 16x4: (r,c)=(lane&15, lane>>4), patch 3x12 as
// 6 v2f/row. Double-buffered Jacobi (v->w, w->v), rolled x2 body.
// Self-tied DPP ghosts: ab/hb persistent regs init'd to frozen reflect ghost;
// ab[k]=update_dpp(ab[k],src[2][k]) = ONE v_mov_b32_dpp, boundary (invalid)
// lanes retain the frozen ghost forever. Horizontal: 6 bpermutes/step
// pipelined one step ahead + cndmask vs frozen col ghost.
// ROUND 14: 5-op/cell math. u' = cc*u + ca*(up+dn) + cb*(l+r) with
// cc = 1-2ca-2cb PRECOMPUTED per (row,col) v2f (18 regs, loop-invariant):
// deletes the two "-2*cv" pk_fmas per v2f (pk_f32 costs 4 pipe-cyc; fp32
// pipe peak == scalar rate, so every pk op removed is real pipe time).
// Ghosts = reflect pad of the INITIAL state (reference pads once).

typedef float v2f __attribute__((ext_vector_type(2)));

constexpr int NXY   = 48;
constexpr int CELLS = NXY * NXY;     // 2304
constexpr int NT    = 10;
constexpr int WPB   = 4;             // waves (images) per block
constexpr int TPB   = 64 * WPB;

// lane i <- lane i-1 within each 16-lane DPP row; invalid (i%16==0) keeps oldv
__device__ __forceinline__ float dpp_up(float oldv, float src) {
    return __int_as_float(__builtin_amdgcn_update_dpp(
        __float_as_int(oldv), __float_as_int(src), 0x111, 0xF, 0xF, false));
}
// lane i <- lane i+1; invalid (i%16==15) keeps oldv
__device__ __forceinline__ float dpp_dn(float oldv, float src) {
    return __int_as_float(__builtin_amdgcn_update_dpp(
        __float_as_int(oldv), __float_as_int(src), 0x101, 0xF, 0xF, false));
}

__global__ __launch_bounds__(TPB)
__attribute__((amdgpu_waves_per_eu(2, 4)))
void pde_heat_kernel(
    const float* __restrict__ u0,
    const float* __restrict__ aw,
    const float* __restrict__ bw,
    float* __restrict__ out)
{
    const int lane = threadIdx.x & 63;
    const int img  = blockIdx.x * WPB + (threadIdx.x >> 6);
    const int r = lane & 15;         // patch-row strip (16 strips of 3 rows)
    const int c = lane >> 4;         // patch-col strip (4 strips of 12 cols)
    const float4* __restrict__ u4 = (const float4*)(u0 + (long long)img * CELLS);
    float4*       __restrict__ o4 = (float4*)(out + (long long)img * CELLS);

    const int fb = r * 36 + c * 3;   // float4 index of patch (row0, col0)

    // ---- direct load: 9 x global_load_dwordx4 -> 6 x v2f per row ----
    v2f v[3][6], w[3][6];
    #pragma unroll
    for (int ii = 0; ii < 3; ++ii)
        #pragma unroll
        for (int k = 0; k < 3; ++k) {
            float4 t = u4[fb + 12 * ii + k];
            v[ii][2*k]   = (v2f){t.x, t.y};
            v[ii][2*k+1] = (v2f){t.z, t.w};
        }

    // ---- coefficients (v_sin/v_cos take REVOLUTIONS: sin(2pi*x) = v_sin(x)) ----
    // alpha(i) scales axis-0 diff: 0.5*dt/dx^2 = 1.152 ; beta(j): dt/dy^2 = 2.304
    const float a0 = aw[0], a1 = aw[1], a2 = aw[2];
    const float b0 = bw[0], b1 = bw[1], b2 = bw[2];
    float ca[3];
    #pragma unroll
    for (int ii = 0; ii < 3; ++ii) {
        float y = (float)(3 * r + ii) * (1.0f / 47.0f);
        ca[ii] = 1.152f * (a0 + a1 * __builtin_amdgcn_sinf(y)
                              + a2 * __builtin_amdgcn_sinf(2.0f * y));
    }
    v2f cb2[6];
    #pragma unroll
    for (int k = 0; k < 6; ++k) {
        float x0 = (float)(12 * c + 2 * k)     * (1.0f / 47.0f);
        float x1 = (float)(12 * c + 2 * k + 1) * (1.0f / 47.0f);
        cb2[k].x = 2.304f * (b0 + b1 * __builtin_amdgcn_cosf(x0)
                                + b2 * __builtin_amdgcn_cosf(2.0f * x0));
        cb2[k].y = 2.304f * (b0 + b1 * __builtin_amdgcn_cosf(x1)
                                + b2 * __builtin_amdgcn_cosf(2.0f * x1));
    }
    // center coefficient cc = 1 - 2ca - 2cb, per (row, col-pair): loop-invariant
    v2f cc[3][6];
    #pragma unroll
    for (int ii = 0; ii < 3; ++ii) {
        float t = 1.0f - 2.0f * ca[ii];
        #pragma unroll
        for (int k = 0; k < 6; ++k) {
            cc[ii][k].x = t - 2.0f * cb2[k].x;
            cc[ii][k].y = t - 2.0f * cb2[k].y;
        }
    }

    // ---- persistent halo registers, initialized to the frozen ghost ----
    // top ghost (r==0) = u0 row 1 = own v[1]; bottom ghost (r==15) = u0 row
    // 46 = 3*15+1 = own v[1]. Boundary lanes are exactly the dpp-invalid
    // lanes -> their ab/hb stay frozen forever at zero cost.
    v2f ab[6], hb[6];
    #pragma unroll
    for (int k = 0; k < 6; ++k) { ab[k] = v[1][k]; hb[k] = v[1][k]; }

    float gH[3];   // frozen horizontal ghosts: col 1 / col 46 (own initial)
    #pragma unroll
    for (int ii = 0; ii < 3; ++ii) gH[ii] = (c == 0) ? v[ii][0].y : v[ii][5].x;

    const int laneL = lane - 16, laneR = lane + 16;
    const bool cLft = (c == 0), cRgt = (c == 3);

    // raw shuffled horizontal halos for the NEXT step (pipelined)
    float hlp[3], hrp[3];
    #pragma unroll
    for (int ii = 0; ii < 3; ++ii) {
        hlp[ii] = __shfl(v[ii][5].y, laneL);   // left neighbor's col 11
        hrp[ii] = __shfl(v[ii][0].x, laneR);   // right neighbor's col 0
    }

    // one Jacobi step: src (all old) -> dst, then issue dst's shuffles
    auto step = [&](const v2f (&src)[3][6], v2f (&dst)[3][6]) {
        // vertical halos: one tied-dest v_mov_b32_dpp each
        #pragma unroll
        for (int k = 0; k < 6; ++k) {
            ab[k].x = dpp_up(ab[k].x, src[2][k].x);
            ab[k].y = dpp_up(ab[k].y, src[2][k].y);
            hb[k].x = dpp_dn(hb[k].x, src[0][k].x);
            hb[k].y = dpp_dn(hb[k].y, src[0][k].y);
        }
        float hl[3], hr[3];
        #pragma unroll
        for (int ii = 0; ii < 3; ++ii) {
            hl[ii] = cLft ? gH[ii] : hlp[ii];
            hr[ii] = cRgt ? gH[ii] : hrp[ii];
        }
        // row 0 (row above = ab)
        #pragma unroll
        for (int k = 0; k < 6; ++k) {
            v2f cv = src[0][k];
            v2f s1 = ab[k] + src[1][k];
            v2f s2;
            s2.x = ((k > 0) ? src[0][k-1].y : hl[0]) + cv.y;
            s2.y = cv.x + ((k < 5) ? src[0][k+1].x : hr[0]);
            dst[0][k] = cc[0][k] * cv + ca[0] * s1 + cb2[k] * s2;  // mul+2 fma
        }
        // row 1 (fully local)
        #pragma unroll
        for (int k = 0; k < 6; ++k) {
            v2f cv = src[1][k];
            v2f s1 = src[0][k] + src[2][k];
            v2f s2;
            s2.x = ((k > 0) ? src[1][k-1].y : hl[1]) + cv.y;
            s2.y = cv.x + ((k < 5) ? src[1][k+1].x : hr[1]);
            dst[1][k] = cc[1][k] * cv + ca[1] * s1 + cb2[k] * s2;
        }
        // row 2 (row below = hb)
        #pragma unroll
        for (int k = 0; k < 6; ++k) {
            v2f cv = src[2][k];
            v2f s1 = src[1][k] + hb[k];
            v2f s2;
            s2.x = ((k > 0) ? src[2][k-1].y : hl[2]) + cv.y;
            s2.y = cv.x + ((k < 5) ? src[2][k+1].x : hr[2]);
            dst[2][k] = cc[2][k] * cv + ca[2] * s1 + cb2[k] * s2;
        }
        // issue NEXT step's shuffles now that dst is final (full-step cover)
        #pragma unroll
        for (int ii = 0; ii < 3; ++ii) {
            hlp[ii] = __shfl(dst[ii][5].y, laneL);
            hrp[ii] = __shfl(dst[ii][0].x, laneR);
        }
    };

    // ---- time loop: rolled x2 (NT=10 even -> final state lands in v) ----
    #pragma unroll 1
    for (int it = 0; it < NT / 2; ++it) {
        step(v, w);
        step(w, v);
    }

    // ---- direct store: 9 x global_store_dwordx4 ----
    #pragma unroll
    for (int ii = 0; ii < 3; ++ii)
        #pragma unroll
        for (int k = 0; k < 3; ++k) {
            float4 t;
            t.x = v[ii][2*k].x;   t.y = v[ii][2*k].y;
            t.z = v[ii][2*k+1].x; t.w = v[ii][2*k+1].y;
            o4[fb + 12 * ii + k] = t;
        }
}

extern "C" void kernel_launch(void* const* d_in, const int* in_sizes, int n_in,
                              void* d_out, int out_size, void* d_ws, size_t ws_size,
                              hipStream_t stream) {
    const float* u0 = (const float*)d_in[0];
    const float* aw = (const float*)d_in[1];
    const float* bw = (const float*)d_in[2];
    float* out = (float*)d_out;

    const int B = in_sizes[0] / CELLS;   // 16384
    pde_heat_kernel<<<B / WPB, TPB, 0, stream>>>(u0, aw, bw, out);
}

// Round 15
// 75.769 us; speedup vs baseline: 1.1301x; 1.0417x over previous
//
#include <hip/hip_runtime.h>

// 10 steps of anisotropic 2D heat stencil, 48x48, B=16384.
// Wave = image = BLOCK (TPB=64): 1-wave workgroups measured the highest
// VALUBusy of any config (round 5: 70%); 4-wave blocks pin at ~46-60%.
// Lane layout 16x4: (r,c)=(lane&15, lane>>4), patch 3x12 as 6 v2f/row.
// Double-buffered Jacobi (v->w, w->v), rolled x2 body (I$-resident).
// 5-op/cell math: u' = cc*u + ca*(up+dn) + cb*(l+r), cc=1-2ca-2cb precomp.
// Self-tied DPP ghosts: ab/hb persistent regs init'd to the frozen reflect
// ghost; one v_mov_b32_dpp each per value; boundary (dpp-invalid) lanes
// retain the ghost forever at zero cost. BOTH halo kinds pipelined: dpp
// updates + bpermute shuffles issued at END of step from dst, consumed next
// step. Ghosts = reflect pad of the INITIAL state (reference pads once).

typedef float v2f __attribute__((ext_vector_type(2)));

constexpr int NXY   = 48;
constexpr int CELLS = NXY * NXY;     // 2304
constexpr int NT    = 10;
constexpr int TPB   = 64;            // ONE wave per block

// lane i <- lane i-1 within each 16-lane DPP row; invalid (i%16==0) keeps oldv
__device__ __forceinline__ float dpp_up(float oldv, float src) {
    return __int_as_float(__builtin_amdgcn_update_dpp(
        __float_as_int(oldv), __float_as_int(src), 0x111, 0xF, 0xF, false));
}
// lane i <- lane i+1; invalid (i%16==15) keeps oldv
__device__ __forceinline__ float dpp_dn(float oldv, float src) {
    return __int_as_float(__builtin_amdgcn_update_dpp(
        __float_as_int(oldv), __float_as_int(src), 0x101, 0xF, 0xF, false));
}

__global__ __launch_bounds__(TPB)
__attribute__((amdgpu_waves_per_eu(2, 4)))
void pde_heat_kernel(
    const float* __restrict__ u0,
    const float* __restrict__ aw,
    const float* __restrict__ bw,
    float* __restrict__ out)
{
    const int lane = threadIdx.x;    // == lane id (single wave)
    const int img  = blockIdx.x;
    const int r = lane & 15;         // patch-row strip (16 strips of 3 rows)
    const int c = lane >> 4;         // patch-col strip (4 strips of 12 cols)
    const float4* __restrict__ u4 = (const float4*)(u0 + (long long)img * CELLS);
    float4*       __restrict__ o4 = (float4*)(out + (long long)img * CELLS);

    const int fb = r * 36 + c * 3;   // float4 index of patch (row0, col0)

    // ---- direct load: 9 x global_load_dwordx4 -> 6 x v2f per row ----
    v2f v[3][6], w[3][6];
    #pragma unroll
    for (int ii = 0; ii < 3; ++ii)
        #pragma unroll
        for (int k = 0; k < 3; ++k) {
            float4 t = u4[fb + 12 * ii + k];
            v[ii][2*k]   = (v2f){t.x, t.y};
            v[ii][2*k+1] = (v2f){t.z, t.w};
        }

    // ---- coefficients (v_sin/v_cos take REVOLUTIONS: sin(2pi*x) = v_sin(x)) ----
    // alpha(i) scales axis-0 diff: 0.5*dt/dx^2 = 1.152 ; beta(j): dt/dy^2 = 2.304
    const float a0 = aw[0], a1 = aw[1], a2 = aw[2];
    const float b0 = bw[0], b1 = bw[1], b2 = bw[2];
    float ca[3];
    #pragma unroll
    for (int ii = 0; ii < 3; ++ii) {
        float y = (float)(3 * r + ii) * (1.0f / 47.0f);
        ca[ii] = 1.152f * (a0 + a1 * __builtin_amdgcn_sinf(y)
                              + a2 * __builtin_amdgcn_sinf(2.0f * y));
    }
    v2f cb2[6];
    #pragma unroll
    for (int k = 0; k < 6; ++k) {
        float x0 = (float)(12 * c + 2 * k)     * (1.0f / 47.0f);
        float x1 = (float)(12 * c + 2 * k + 1) * (1.0f / 47.0f);
        cb2[k].x = 2.304f * (b0 + b1 * __builtin_amdgcn_cosf(x0)
                                + b2 * __builtin_amdgcn_cosf(2.0f * x0));
        cb2[k].y = 2.304f * (b0 + b1 * __builtin_amdgcn_cosf(x1)
                                + b2 * __builtin_amdgcn_cosf(2.0f * x1));
    }
    // center coefficient cc = 1 - 2ca - 2cb, per (row, col-pair): loop-invariant
    v2f cc[3][6];
    #pragma unroll
    for (int ii = 0; ii < 3; ++ii) {
        float t = 1.0f - 2.0f * ca[ii];
        #pragma unroll
        for (int k = 0; k < 6; ++k) {
            cc[ii][k].x = t - 2.0f * cb2[k].x;
            cc[ii][k].y = t - 2.0f * cb2[k].y;
        }
    }

    // ---- persistent halo registers, init'd to the frozen ghost ----
    // top ghost (r==0) = u0 row 1 = own v[1]; bottom ghost (r==15) = row 46
    // = 3*15+1 = own v[1]. Boundary lanes are exactly the dpp-invalid lanes.
    v2f ab[6], hb[6];
    #pragma unroll
    for (int k = 0; k < 6; ++k) { ab[k] = v[1][k]; hb[k] = v[1][k]; }

    float gH[3];   // frozen horizontal ghosts: col 1 / col 46 (own initial)
    #pragma unroll
    for (int ii = 0; ii < 3; ++ii) gH[ii] = (c == 0) ? v[ii][0].y : v[ii][5].x;

    const int laneL = lane - 16, laneR = lane + 16;
    const bool cLft = (c == 0), cRgt = (c == 3);

    // prime BOTH halo pipelines for step 0 (from initial state)
    #pragma unroll
    for (int k = 0; k < 6; ++k) {
        ab[k].x = dpp_up(ab[k].x, v[2][k].x);
        ab[k].y = dpp_up(ab[k].y, v[2][k].y);
        hb[k].x = dpp_dn(hb[k].x, v[0][k].x);
        hb[k].y = dpp_dn(hb[k].y, v[0][k].y);
    }
    float hlp[3], hrp[3];
    #pragma unroll
    for (int ii = 0; ii < 3; ++ii) {
        hlp[ii] = __shfl(v[ii][5].y, laneL);   // left neighbor's col 11
        hrp[ii] = __shfl(v[ii][0].x, laneR);   // right neighbor's col 0
    }

    // one Jacobi step: src (old) -> dst using pre-staged halos, then stage
    // next step's halos from dst (unless last step)
    auto step = [&](const v2f (&src)[3][6], v2f (&dst)[3][6], bool stage) {
        float hl[3], hr[3];
        #pragma unroll
        for (int ii = 0; ii < 3; ++ii) {
            hl[ii] = cLft ? gH[ii] : hlp[ii];
            hr[ii] = cRgt ? gH[ii] : hrp[ii];
        }
        // row 0 (row above = ab)
        #pragma unroll
        for (int k = 0; k < 6; ++k) {
            v2f cv = src[0][k];
            v2f s1 = ab[k] + src[1][k];
            v2f s2;
            s2.x = ((k > 0) ? src[0][k-1].y : hl[0]) + cv.y;
            s2.y = cv.x + ((k < 5) ? src[0][k+1].x : hr[0]);
            dst[0][k] = cc[0][k] * cv + ca[0] * s1 + cb2[k] * s2;
        }
        // row 1 (fully local)
        #pragma unroll
        for (int k = 0; k < 6; ++k) {
            v2f cv = src[1][k];
            v2f s1 = src[0][k] + src[2][k];
            v2f s2;
            s2.x = ((k > 0) ? src[1][k-1].y : hl[1]) + cv.y;
            s2.y = cv.x + ((k < 5) ? src[1][k+1].x : hr[1]);
            dst[1][k] = cc[1][k] * cv + ca[1] * s1 + cb2[k] * s2;
        }
        // row 2 (row below = hb)
        #pragma unroll
        for (int k = 0; k < 6; ++k) {
            v2f cv = src[2][k];
            v2f s1 = src[1][k] + hb[k];
            v2f s2;
            s2.x = ((k > 0) ? src[2][k-1].y : hl[2]) + cv.y;
            s2.y = cv.x + ((k < 5) ? src[2][k+1].x : hr[2]);
            dst[2][k] = cc[2][k] * cv + ca[2] * s1 + cb2[k] * s2;
        }
        if (stage) {
            // vertical halos for next step: one tied-dest v_mov_b32_dpp each
            #pragma unroll
            for (int k = 0; k < 6; ++k) {
                ab[k].x = dpp_up(ab[k].x, dst[2][k].x);
                ab[k].y = dpp_up(ab[k].y, dst[2][k].y);
                hb[k].x = dpp_dn(hb[k].x, dst[0][k].x);
                hb[k].y = dpp_dn(hb[k].y, dst[0][k].y);
            }
            // horizontal halos for next step (full-step latency cover)
            #pragma unroll
            for (int ii = 0; ii < 3; ++ii) {
                hlp[ii] = __shfl(dst[ii][5].y, laneL);
                hrp[ii] = __shfl(dst[ii][0].x, laneR);
            }
        }
    };

    // ---- time loop: rolled x2 (NT=10 even -> final state lands in v) ----
    #pragma unroll 1
    for (int it = 0; it < NT / 2 - 1; ++it) {
        step(v, w, true);
        step(w, v, true);
    }
    step(v, w, true);
    step(w, v, false);               // last step: skip dead halo staging

    // ---- direct store: 9 x global_store_dwordx4 ----
    #pragma unroll
    for (int ii = 0; ii < 3; ++ii)
        #pragma unroll
        for (int k = 0; k < 3; ++k) {
            float4 t;
            t.x = v[ii][2*k].x;   t.y = v[ii][2*k].y;
            t.z = v[ii][2*k+1].x; t.w = v[ii][2*k+1].y;
            o4[fb + 12 * ii + k] = t;
        }
}

extern "C" void kernel_launch(void* const* d_in, const int* in_sizes, int n_in,
                              void* d_out, int out_size, void* d_ws, size_t ws_size,
                              hipStream_t stream) {
    const float* u0 = (const float*)d_in[0];
    const float* aw = (const float*)d_in[1];
    const float* bw = (const float*)d_in[2];
    float* out = (float*)d_out;

    const int B = in_sizes[0] / CELLS;   // 16384
    pde_heat_kernel<<<B, TPB, 0, stream>>>(u0, aw, bw, out);
}